// Round 5
// baseline (1024.307 us; speedup 1.0000x reference)
//
#include <hip/hip_runtime.h>

typedef _Float16 half2v __attribute__((ext_vector_type(2)));

#define T_LEN 1024
#define NBATCH 1024
#define HID 20

#if defined(__has_builtin)
#if __has_builtin(__builtin_amdgcn_fdot2)
#define HAVE_FDOT2 1
#endif
#endif

__device__ __forceinline__ float fdot2_(half2v a, half2v b, float c) {
#ifdef HAVE_FDOT2
    return __builtin_amdgcn_fdot2(a, b, c, false);
#else
    return c + (float)a[0] * (float)b[0] + (float)a[1] * (float)b[1];
#endif
}

__device__ __forceinline__ half2v pack2(float a, float b) {
    half2v r;
    r[0] = (_Float16)a;
    r[1] = (_Float16)b;
    return r;
}

// tanh via sigmoid identity
__device__ __forceinline__ float tanh_s(float z) {
    return 2.0f / (1.0f + __expf(-2.0f * z)) - 1.0f;
}

// Load 20 f16 (one padded 24-half, 48B row, 16B-aligned) into 10 half2.
__device__ __forceinline__ void load_h20(const _Float16* row, half2v hp[10]) {
    uint4 q0 = *(const uint4*)(row);
    uint4 q1 = *(const uint4*)(row + 8);
    uint2 q2 = *(const uint2*)(row + 16);
    hp[0] = __builtin_bit_cast(half2v, q0.x);
    hp[1] = __builtin_bit_cast(half2v, q0.y);
    hp[2] = __builtin_bit_cast(half2v, q0.z);
    hp[3] = __builtin_bit_cast(half2v, q0.w);
    hp[4] = __builtin_bit_cast(half2v, q1.x);
    hp[5] = __builtin_bit_cast(half2v, q1.y);
    hp[6] = __builtin_bit_cast(half2v, q1.z);
    hp[7] = __builtin_bit_cast(half2v, q1.w);
    hp[8] = __builtin_bit_cast(half2v, q2.x);
    hp[9] = __builtin_bit_cast(half2v, q2.y);
}

// Spin until *p >= v, then compiler barrier (prevents hoisting data reads
// above the spin; DS ops are in-order per wave so HW order is safe).
__device__ __forceinline__ void spin_ge(const volatile int* p, int v) {
    while (*p < v) {}
    __asm__ __volatile__("" ::: "memory");
}

// Layer-pipelined 3-wave block, NO per-iteration barrier.
// Wave l owns layer l and loops over its own t, synchronized with wave l-1
// via monotone LDS progress flags (prog) and throttled by consumer flags
// (done). Ring depth 2. Lanes 0..19 -> gates i(j),g(j); lanes 20..39 ->
// f(j),o(j); lanes 40..63 idle.
__global__ void __launch_bounds__(192, 3) lstm3_async(
    const float* __restrict__ x,
    const float* __restrict__ wih0, const float* __restrict__ whh0,
    const float* __restrict__ bih0, const float* __restrict__ bhh0,
    const float* __restrict__ wih1, const float* __restrict__ whh1,
    const float* __restrict__ bih1, const float* __restrict__ bhh1,
    const float* __restrict__ wih2, const float* __restrict__ whh2,
    const float* __restrict__ bih2, const float* __restrict__ bhh2,
    const float* __restrict__ fcw, const float* __restrict__ fcb,
    float* __restrict__ out)
{
    __shared__ __align__(16) float xlds[T_LEN];         // staged input, 4 KB
    __shared__ __align__(16) _Float16 rings[3][2][24];  // h rings, depth 2
    __shared__ int prog[3];   // steps published by wave l (h_l(t) committed)
    __shared__ int done[3];   // steps consumed by wave l (reads of ring l-1)

    const int tid = threadIdx.x;
    const int wv = tid / 64;
    const int lane = tid & 63;
    const int b = blockIdx.x;

    // stage x (coalesced float4), zero rings + flags
    {
        const float4* x4 = (const float4*)(x + (long)b * T_LEN);
        float4* xl4 = (float4*)xlds;
        for (int i = tid; i < T_LEN / 4; i += 192) xl4[i] = x4[i];
        if (tid < 3 * 2 * 24) ((_Float16*)rings)[tid] = (_Float16)0.0f;
        if (tid < 3) { prog[tid] = 0; done[tid] = 0; }
    }

    const int j = (lane < 40) ? (lane % 20) : 0;
    const bool low = lane < 20;
    const int r0 = low ? j : (HID + j);                  // i-row / f-row
    const int r1 = low ? (2 * HID + j) : (3 * HID + j);  // g-row / o-row
    const int srcl = low ? lane : (lane - 20);

    // gate1 activation: tanh on g-lanes (low), sigmoid on o-lanes (high)
    const float kK = low ? -2.0f : -1.0f;
    const float kA = low ? 2.0f : 1.0f;
    const float kB = low ? -1.0f : 0.0f;

    const float* whh = (wv == 0) ? whh0 : (wv == 1) ? whh1 : whh2;
    const float* wih = (wv == 0) ? wih0 : (wv == 1) ? wih1 : wih2;
    const float* bih = (wv == 0) ? bih0 : (wv == 1) ? bih1 : bih2;
    const float* bhh = (wv == 0) ? bhh0 : (wv == 1) ? bhh1 : bhh2;

    half2v Whh[2][10];
    half2v Wih[2][10];
    float wx0 = 0.0f, wx1 = 0.0f;
    float bias0, bias1;
    {
#pragma unroll
        for (int k4 = 0; k4 < 5; ++k4) {
            float4 v0 = *(const float4*)(whh + r0 * HID + 4 * k4);
            Whh[0][2 * k4]     = pack2(v0.x, v0.y);
            Whh[0][2 * k4 + 1] = pack2(v0.z, v0.w);
            float4 v1 = *(const float4*)(whh + r1 * HID + 4 * k4);
            Whh[1][2 * k4]     = pack2(v1.x, v1.y);
            Whh[1][2 * k4 + 1] = pack2(v1.z, v1.w);
        }
        bias0 = bih[r0] + bhh[r0];
        bias1 = bih[r1] + bhh[r1];
        if (wv == 0) {
            wx0 = wih[r0];  // w_ih0 is (80,1)
            wx1 = wih[r1];
        } else {
#pragma unroll
            for (int k4 = 0; k4 < 5; ++k4) {
                float4 v0 = *(const float4*)(wih + r0 * HID + 4 * k4);
                Wih[0][2 * k4]     = pack2(v0.x, v0.y);
                Wih[0][2 * k4 + 1] = pack2(v0.z, v0.w);
                float4 v1 = *(const float4*)(wih + r1 * HID + 4 * k4);
                Wih[1][2 * k4]     = pack2(v1.x, v1.y);
                Wih[1][2 * k4 + 1] = pack2(v1.z, v1.w);
            }
        }
    }

    __syncthreads();  // one-time: x, rings, flags visible

    _Float16* const wp_base = &rings[wv][0][0];
    const _Float16* const rb_base = (wv > 0) ? &rings[wv - 1][0][0]
                                             : &rings[0][0][0];
    volatile int* const vprog = (volatile int*)prog;
    volatile int* const vdone = (volatile int*)done;

    float c = 0.0f;                                    // cell (lanes 20..39)
    float dA0 = 0.f, dA1 = 0.f, gA0 = 0.f, gA1 = 0.f;  // own-h partials (h(-1)=0)

    for (int t = 0; t < T_LEN; ++t) {
        const int p24 = (t & 1) * 24;
        _Float16* const wp = wp_base + p24;

        float pre0, pre1;
        if (wv == 0) {
            // throttle: don't overwrite ring slot wave1 hasn't consumed
            spin_ge(vdone + 1, t - 1);
            const float xt = xlds[t];
            pre0 = bias0 + dA0 + dA1 + wx0 * xt;
            pre1 = bias1 + gA0 + gA1 + wx1 * xt;
        } else {
            // wait producer; wave1 also throttles on wave2's consumption
            if (wv == 1) spin_ge(vdone + 2, t - 1);
            spin_ge(vprog + (wv - 1), t + 1);
            half2v hbel[10];
            load_h20(rb_base + p24, hbel);
            float d2 = 0.f, d3 = 0.f, g2 = 0.f, g3 = 0.f;
#pragma unroll
            for (int k = 0; k < 5; ++k) {
                d2 = fdot2_(Wih[0][k],     hbel[k],     d2);
                d3 = fdot2_(Wih[0][k + 5], hbel[k + 5], d3);
                g2 = fdot2_(Wih[1][k],     hbel[k],     g2);
                g3 = fdot2_(Wih[1][k + 5], hbel[k + 5], g3);
            }
            pre0 = bias0 + (dA0 + dA1) + (d2 + d3);
            pre1 = bias1 + (gA0 + gA1) + (g2 + g3);
            // publish consumption (hbel fully read: data-dep + in-order DS)
            __asm__ __volatile__("" ::: "memory");
            vdone[wv] = t + 1;
        }

        float a0 = 1.0f / (1.0f + __expf(-pre0));         // sigma(i)/sigma(f)
        float a1 = kA / (1.0f + __expf(kK * pre1)) + kB;  // tanh(g)/sigma(o)
        float u = a0 * a1;
        float uf = __shfl(u, srcl, 64);
        if (lane >= 20 && lane < 40) {
            float cn = a0 * c + uf;                 // a0 = sigma(f)
            c = cn;
            wp[j] = (_Float16)(a1 * tanh_s(cn));    // h(t) = sigma(o)*tanh(c)
        }

        if (wv < 2) {
            __threadfence_block();   // drain h-write before publishing
            vprog[wv] = t + 1;
        }

        // read back own h(t) (no sync needed: our own wave, in-order DS)
        half2v hown[10];
        load_h20(wp, hown);
        dA0 = 0.f; dA1 = 0.f; gA0 = 0.f; gA1 = 0.f;
#pragma unroll
        for (int k = 0; k < 5; ++k) {
            dA0 = fdot2_(Whh[0][k],     hown[k],     dA0);
            dA1 = fdot2_(Whh[0][k + 5], hown[k + 5], dA1);
            gA0 = fdot2_(Whh[1][k],     hown[k],     gA0);
            gA1 = fdot2_(Whh[1][k + 5], hown[k + 5], gA1);
        }
    }

    // FC epilogue: wave 2 owns h2(T-1) = rings[2][(T_LEN-1)&1] = rings[2][1]
    if (wv == 2 && lane < 2) {
        float acc = fcb[lane];
        const _Float16* h2 = &rings[2][1][0];
#pragma unroll
        for (int k = 0; k < HID; ++k) {
            acc += fcw[lane * HID + k] * (float)h2[k];
        }
        out[b * 2 + lane] = acc;
    }
}

extern "C" void kernel_launch(void* const* d_in, const int* in_sizes, int n_in,
                              void* d_out, int out_size, void* d_ws, size_t ws_size,
                              hipStream_t stream) {
    const float* x    = (const float*)d_in[0];
    const float* wih0 = (const float*)d_in[1];
    const float* whh0 = (const float*)d_in[2];
    const float* bih0 = (const float*)d_in[3];
    const float* bhh0 = (const float*)d_in[4];
    const float* wih1 = (const float*)d_in[5];
    const float* whh1 = (const float*)d_in[6];
    const float* bih1 = (const float*)d_in[7];
    const float* bhh1 = (const float*)d_in[8];
    const float* wih2 = (const float*)d_in[9];
    const float* whh2 = (const float*)d_in[10];
    const float* bih2 = (const float*)d_in[11];
    const float* bhh2 = (const float*)d_in[12];
    const float* fcw  = (const float*)d_in[13];
    const float* fcb  = (const float*)d_in[14];

    lstm3_async<<<dim3(NBATCH), dim3(192), 0, stream>>>(
        x, wih0, whh0, bih0, bhh0,
        wih1, whh1, bih1, bhh1,
        wih2, whh2, bih2, bhh2,
        fcw, fcb, (float*)d_out);
}